// Round 1
// baseline (100.883 us; speedup 1.0000x reference)
//
#include <hip/hip_runtime.h>
#include <stdint.h>

// Problem constants (from reference setup_inputs / module constants)
#define NB 32
#define NM 80
#define NT 2000
#define MSEL 16
#define NWPW 64          // windows kept per window-length (MAX_TIME_WINDOWS)
#define NWIN 128         // 64 windows of w=5 + 64 windows of w=10
#define NCOLS 2048.0f    // MSEL * NWPW * 2 window lengths

struct Params {
    int mel[MSEL];
    int start[NWIN];     // [0:64) -> w=5 starts, [64:128) -> w=10 starts
};

// ---------------------------------------------------------------------------
// Kernel A: one block per (b, mel_sel). Stage both rows to LDS, each thread
// computes one window's cosine distance via the collapsed-head formulation,
// block writes (sum_D, sum_relu(margin-D)) to ws[2*blk ..].
// ---------------------------------------------------------------------------
__global__ __launch_bounds__(128) void asn_win_kernel(
    const float* __restrict__ A, const float* __restrict__ P,
    const float* __restrict__ W1a, const float* __restrict__ W2a,
    const float* __restrict__ W1p, const float* __restrict__ W2p,
    float* __restrict__ ws, Params prm)
{
    __shared__ float4 sA4[NT / 4];
    __shared__ float4 sP4[NT / 4];
    __shared__ float sK[4];      // K[ia*2+ip], ia/ip: 1 = value >= 0
    __shared__ float sSA[2];
    __shared__ float sSP[2];
    __shared__ float wsum[2][2];

    float* sA = (float*)sA4;
    float* sP = (float*)sP4;

    const int blk = blockIdx.x;      // 0..511
    const int b   = blk >> 4;
    const int msi = blk & 15;
    const int m   = prm.mel[msi];
    const int tid = threadIdx.x;

    if (tid == 0) {
        // Collapsed head coefficients:
        //   head(a)[o] = a * (a>=0 ? cap[o] : can[o])
        // cap[o] = sum_{c: W1[c]>0} W1[c]*W2[o,c];  can: W1[c]<0 terms.
        float cap[8], can[8], cqp[8], cqn[8];
        #pragma unroll
        for (int o = 0; o < 8; ++o) { cap[o]=0.f; can[o]=0.f; cqp[o]=0.f; cqn[o]=0.f; }
        #pragma unroll
        for (int c = 0; c < 8; ++c) {
            float wa = W1a[c], wp = W1p[c];
            #pragma unroll
            for (int o = 0; o < 8; ++o) {
                float ta = wa * W2a[o * 8 + c];
                float tp = wp * W2p[o * 8 + c];
                if (wa > 0.f) cap[o] += ta; else if (wa < 0.f) can[o] += ta;
                if (wp > 0.f) cqp[o] += tp; else if (wp < 0.f) cqn[o] += tp;
            }
        }
        float kpp=0.f,kpn=0.f,knp=0.f,knn=0.f,sap=0.f,san=0.f,spp=0.f,spn=0.f;
        #pragma unroll
        for (int o = 0; o < 8; ++o) {
            kpp += cap[o]*cqp[o];  kpn += cap[o]*cqn[o];
            knp += can[o]*cqp[o];  knn += can[o]*cqn[o];
            sap += cap[o]*cap[o];  san += can[o]*can[o];
            spp += cqp[o]*cqp[o];  spn += cqn[o]*cqn[o];
        }
        sK[3]=kpp; sK[2]=kpn; sK[1]=knp; sK[0]=knn;
        sSA[1]=sap; sSA[0]=san;
        sSP[1]=spp; sSP[0]=spn;
    }

    // Stage the two selected rows (contiguous, 16B-aligned: row = 8000 B)
    const float4* arow = (const float4*)(A + ((size_t)b * NM + m) * NT);
    const float4* prow = (const float4*)(P + ((size_t)b * NM + m) * NT);
    for (int t = tid; t < NT / 4; t += 128) {
        sA4[t] = arow[t];
        sP4[t] = prow[t];
    }
    __syncthreads();

    // One window per thread
    const int w = (tid < 64) ? 5 : 10;
    const int s = prm.start[tid];
    float dot = 0.f, na = 0.f, npv = 0.f;
    for (int t = 0; t < w; ++t) {
        float a = sA[s + t];
        float p = sP[s + t];
        int ia = (a >= 0.f) ? 1 : 0;
        int ip = (p >= 0.f) ? 1 : 0;
        dot += a * p * sK[ia * 2 + ip];
        na  += a * a * sSA[ia];
        npv += p * p * sSP[ip];
    }
    float nu = fmaxf(sqrtf(na),  1e-12f);
    float nv = fmaxf(sqrtf(npv), 1e-12f);
    float dist = 1.f - dot / (nu * nv);
    float rd   = fmaxf(0.2f - dist, 0.f);   // relu(MARGIN - D)

    // reduce 128 threads -> 2 values
    float s1 = dist, s2 = rd;
    for (int off = 32; off; off >>= 1) {
        s1 += __shfl_down(s1, off);
        s2 += __shfl_down(s2, off);
    }
    if ((tid & 63) == 0) {
        wsum[tid >> 6][0] = s1;
        wsum[tid >> 6][1] = s2;
    }
    __syncthreads();
    if (tid == 0) {
        ws[2 * blk]     = wsum[0][0] + wsum[1][0];
        ws[2 * blk + 1] = wsum[0][1] + wsum[1][1];
    }
}

// ---------------------------------------------------------------------------
// Kernel B: single block. Mask-reduce the 512 per-block partials into
// stc_loss (out[0]) and coh_score[b] (out[1..32]).
// ---------------------------------------------------------------------------
__global__ __launch_bounds__(256) void asn_final_kernel(
    const float* __restrict__ ws, const int* __restrict__ y,
    float* __restrict__ out)
{
    __shared__ float sr[256];
    __shared__ float ss[256];
    const int tid = threadIdx.x;

    float aR = 0.f, aS = 0.f;
    for (int k = tid; k < 512; k += 256) {
        int b = k >> 4;
        if (y[b] == 0) aR += ws[2 * k];
        else           aS += ws[2 * k + 1];
    }
    sr[tid] = aR; ss[tid] = aS;
    __syncthreads();
    for (int off = 128; off; off >>= 1) {
        if (tid < off) { sr[tid] += sr[tid + off]; ss[tid] += ss[tid + off]; }
        __syncthreads();
    }

    if (tid < 32) {
        const float* base = ws + 2 * (tid * 16);
        float sum = 0.f;
        #pragma unroll
        for (int i = 0; i < 16; ++i) sum += base[2 * i];
        out[1 + tid] = 1.f - sum * (1.0f / NCOLS);   // coh_score[b]
    }
    if (tid == 0) {
        int nr = 0, ns = 0;
        for (int b = 0; b < NB; ++b) { int yb = y[b]; nr += (yb == 0); ns += (yb == 1); }
        float lr = sr[0] / (NCOLS * (float)(nr > 0 ? nr : 1));
        float ls = ss[0] / (NCOLS * (float)(ns > 0 ? ns : 1));
        out[0] = lr + 0.5f * ls;                     // stc_loss
    }
}

// ---------------------------------------------------------------------------
// Host: bit-exact replication of np.random.default_rng(123).permutation(80)
// (SeedSequence -> PCG64 XSL-RR 128/64 -> random_interval Fisher-Yates)
// and of np.linspace(...).astype(int64) window-start subsampling.
// Pure CPU work, deterministic, graph-capture safe.
// ---------------------------------------------------------------------------
static void compute_params(Params& prm)
{
    // ---- numpy SeedSequence(123) ----
    const uint32_t INIT_A = 0x43b0d7e5u, MULT_A = 0x931e8875u;
    const uint32_t INIT_B = 0x8b51f9ddu, MULT_B = 0x58f38dedu;
    const uint32_t MIX_L  = 0xca01f9ddu, MIX_R  = 0x4973f715u;

    uint32_t hc = INIT_A;
    auto hashmix = [&](uint32_t v) -> uint32_t {
        v ^= hc; hc *= MULT_A; v *= hc; v ^= v >> 16; return v;
    };
    auto mix = [](uint32_t x, uint32_t y) -> uint32_t {
        uint32_t r = (x * 0xca01f9ddu) ^ (y * 0x4973f715u);
        r ^= r >> 16; return r;
    };
    (void)MIX_L; (void)MIX_R;

    uint32_t pool[4];
    const uint32_t entropy[1] = { 123u };
    for (int i = 0; i < 4; ++i) pool[i] = hashmix(i < 1 ? entropy[i] : 0u);
    for (int s = 0; s < 4; ++s)
        for (int d = 0; d < 4; ++d)
            if (s != d) pool[d] = mix(pool[d], hashmix(pool[s]));

    // generate_state(4, uint64) -> 8 uint32 words, LE-paired
    uint32_t w32[8];
    uint32_t hc2 = INIT_B;
    for (int i = 0; i < 8; ++i) {
        uint32_t v = pool[i & 3];
        v ^= hc2; hc2 *= MULT_B; v *= hc2; v ^= v >> 16;
        w32[i] = v;
    }
    uint64_t sd[4];
    for (int i = 0; i < 4; ++i)
        sd[i] = (uint64_t)w32[2 * i] | ((uint64_t)w32[2 * i + 1] << 32);

    // ---- PCG64 (setseq 128, XSL-RR output) ----
    typedef __uint128_t u128;
    const u128 MULT = ((u128)0x2360ed051fc65da4ULL << 64) | 0x4385df649fccf645ULL;
    u128 initstate = ((u128)sd[0] << 64) | sd[1];
    u128 initseq   = ((u128)sd[2] << 64) | sd[3];
    u128 state = 0, inc = (initseq << 1) | 1;
    state = state * MULT + inc;
    state += initstate;
    state = state * MULT + inc;

    bool has32 = false; uint32_t buf32 = 0;
    auto next64 = [&]() -> uint64_t {
        state = state * MULT + inc;                 // step THEN output
        uint64_t hi = (uint64_t)(state >> 64);
        uint64_t lo = (uint64_t)state;
        uint64_t x = hi ^ lo;
        unsigned rot = (unsigned)(state >> 122);    // top 6 bits
        return (x >> rot) | (x << ((64u - rot) & 63u));
    };
    auto next32 = [&]() -> uint32_t {
        if (has32) { has32 = false; return buf32; }
        uint64_t v = next64();
        has32 = true; buf32 = (uint32_t)(v >> 32);  // high half buffered
        return (uint32_t)v;                          // low half first
    };

    // ---- Generator.permutation(80): Fisher-Yates with random_interval ----
    int perm[NM];
    for (int i = 0; i < NM; ++i) perm[i] = i;
    for (int i = NM - 1; i >= 1; --i) {
        uint32_t mask = (uint32_t)i;
        mask |= mask >> 1; mask |= mask >> 2; mask |= mask >> 4;
        mask |= mask >> 8; mask |= mask >> 16;
        uint32_t j;
        do { j = next32() & mask; } while (j > (uint32_t)i);
        int tmp = perm[i]; perm[i] = perm[(int)j]; perm[(int)j] = tmp;
    }
    for (int i = 0; i < MSEL; ++i) prm.mel[i] = perm[i];

    // ---- window starts ----
    // hop_frames=3. w=5: full starts 0..1995 step 3 (666) -> linspace(0,665,64)
    //               w=10: full starts 0..1989 step 3 (664) -> linspace(0,663,64)
    {
        const double step = 665.0 / 63.0;
        for (int i = 0; i < 64; ++i) {
            long long sel = (i == 63) ? 665LL : (long long)((double)i * step);
            prm.start[i] = (int)(3LL * sel);
        }
    }
    {
        const double step = 663.0 / 63.0;
        for (int i = 0; i < 64; ++i) {
            long long sel = (i == 63) ? 663LL : (long long)((double)i * step);
            prm.start[64 + i] = (int)(3LL * sel);
        }
    }
}

extern "C" void kernel_launch(void* const* d_in, const int* in_sizes, int n_in,
                              void* d_out, int out_size, void* d_ws, size_t ws_size,
                              hipStream_t stream)
{
    const float* A   = (const float*)d_in[0];
    const float* P   = (const float*)d_in[1];
    const int*   y   = (const int*)d_in[2];
    const float* W1a = (const float*)d_in[3];
    const float* W2a = (const float*)d_in[4];
    const float* W1p = (const float*)d_in[5];
    const float* W2p = (const float*)d_in[6];
    float* out = (float*)d_out;
    float* ws  = (float*)d_ws;   // needs 512*2 floats = 4 KB

    Params prm;
    compute_params(prm);

    asn_win_kernel<<<dim3(NB * MSEL), dim3(128), 0, stream>>>(
        A, P, W1a, W2a, W1p, W2p, ws, prm);
    asn_final_kernel<<<dim3(1), dim3(256), 0, stream>>>(ws, y, out);
}